// Round 20
// baseline (78.142 us; speedup 1.0000x reference)
//
#include <hip/hip_runtime.h>

// Conv3D implicit GEMM, round 20: aligned-B remap — fragment f covers
// wo = 4*(l31&15)+f, hosub = l31>>4 (wave = 64co x 2ho x 64wo). Per-lane B
// base dword 4*(l31&15) is 16B-aligned and wo-step = 1 dword, so all four
// fragments are register windows of one 8-dword pool read by 2 ds_read_b128
// (replaces 16 ds_read_b32). 4-wave/256-thr blocks, r19 A-sharing (4-slot,
// barrier per 2 chunks), acc 128 AGPR.
// x (8,3,16,112,112) f32, w (64,3,5,7,7), bias (64,) -> out (8,64,16,56,56) f32

typedef __attribute__((ext_vector_type(8)))  short short8;
typedef __attribute__((ext_vector_type(4)))  float f32x4;
typedef __attribute__((ext_vector_type(16))) float f32x16;

#define CI 3
#define DI 16
#define HI 112
#define WI 112
#define CO 64
#define DO_ 16
#define HO 56
#define WO 56
#define HW_IN 12544
#define DHWO 50176

#define NROW 105
#define NCH 27

// xpad: bf16 [8][3][20 dpad][119 hpad][120 slots]; slot s = win s-3
#define XP_ROW 120
#define XP_H   119
#define XP_D   20
#define XPAD_BYTES  (8*3*XP_D*XP_H*XP_ROW*2)   // 13,708,800
#define WBUF_OFF    XPAD_BYTES
#define WS_NEED     (WBUF_OFF + NCH*4*64*16 + 4096)

#define LR 13               // staged h-rows per (c,plane): 2*4ho + 5
#define SEG_SH (LR*XP_ROW)  // 1560 shorts (3120 B)
#define SEG_DW (SEG_SH/2)   // 780
#define ROW_DW (XP_ROW/2)   // 60
#define ALDS_SH (18*SEG_SH + 128)   // short-index of A LDS base (after pad)

__device__ __forceinline__ unsigned short f2bf(float f) {
    unsigned u = __float_as_uint(f);
    return (unsigned short)((u + 0x7FFFu + ((u >> 16) & 1u)) >> 16);
}
__device__ __forceinline__ unsigned pk_bf16(float a, float b) {
    unsigned r;
    asm("v_cvt_pk_bf16_f32 %0, %1, %2" : "=v"(r) : "v"(a), "v"(b));
    return r;
}

// clamped row -> LDS dword base within (ddl=0, hoL=0)
__device__ __forceinline__ constexpr int rb2(int r) {
    const int rc = (r > 104) ? 104 : r;
    const int c  = rc / 35;
    const int kd = (rc / 7) % 5;
    const int kh = rc % 7;
    return (c * 6 + kd) * SEG_DW + kh * ROW_DW;
}

// ---------- fused prep: xpad (15 s8-groups/row) + weights 32x32 layout ----------
#define XP_THREADS (8*3*XP_D*XP_H*15)   // 856,800
#define XP_BLOCKS  3347

__global__ void prep_all(const float* __restrict__ x, const float* __restrict__ wgt,
                         unsigned* __restrict__ xp, short8* __restrict__ wbuf) {
    if (blockIdx.x < XP_BLOCKS) {
        const int g = blockIdx.x * 256 + threadIdx.x;
        if (g >= XP_THREADS) return;
        const int s8 = g % 15;
        int r = g / 15;
        const int hp = r % XP_H; r /= XP_H;
        const int dp = r % XP_D; r /= XP_D;
        const int c  = r % 3;
        const int n  = r / 3;
        const int din = dp - 2, hin = hp - 3;
        const bool rowok = ((unsigned)din < (unsigned)DI) && ((unsigned)hin < (unsigned)HI);
        float v[8];
        const int w0 = 8 * s8 - 3;
        if (rowok && s8 >= 1 && s8 <= 13) {
            const float* xr = x + ((n * CI + c) * DI + din) * HW_IN + hin * WI + w0;
            #pragma unroll
            for (int j = 0; j < 8; ++j) v[j] = xr[j];
        } else if (rowok && (s8 == 0 || s8 == 14)) {
            const float* xr = x + ((n * CI + c) * DI + din) * HW_IN + hin * WI;
            #pragma unroll
            for (int j = 0; j < 8; ++j) {
                const int w = w0 + j;
                v[j] = ((unsigned)w < (unsigned)WI) ? xr[w] : 0.0f;
            }
        } else {
            #pragma unroll
            for (int j = 0; j < 8; ++j) v[j] = 0.0f;
        }
        uint4 o;
        o.x = pk_bf16(v[0], v[1]); o.y = pk_bf16(v[2], v[3]);
        o.z = pk_bf16(v[4], v[5]); o.w = pk_bf16(v[6], v[7]);
        *reinterpret_cast<uint4*>(xp + 4 * (size_t)g) = o;
    } else {
        // weights -> 32x32 fragment layout: frag cf = ch*4 + ks*2 + a
        // lane: co = a*32 + (lane&31), row r = ch*4 + ks*2 + (lane>>5), kw = j
        const int t = (blockIdx.x - XP_BLOCKS) * 256 + threadIdx.x;  // 0..6911
        const int lane = t & 63;
        const int cf   = t >> 6;           // 0..107
        const int q    = cf & 3;
        const int a    = q & 1;
        const int ks   = q >> 1;
        const int ch   = cf >> 2;
        const int l31  = lane & 31;
        const int hl   = lane >> 5;
        const int co   = a * 32 + l31;
        const int r    = ch * 4 + ks * 2 + hl;
        const int rc   = (r > 104) ? 104 : r;
        const int c    = rc / 35;
        const int kd   = (rc / 7) % 5;
        const int kh   = rc % 7;
        const float* wsrc = wgt + (((co * CI + c) * 5 + kd) * 7 + kh) * 7;
        short8 v;
        #pragma unroll
        for (int j = 0; j < 8; ++j) {
            float w = (r < NROW && j < 7) ? wsrc[j] : 0.0f;
            v[j] = (short)f2bf(w);
        }
        wbuf[(size_t)cf * 64 + lane] = v;
    }
}

#define MFMA32(A, B, C) __builtin_amdgcn_mfma_f32_32x32x16_bf16(A, B, C, 0, 0, 0)
#define GLDS(src, dst) __builtin_amdgcn_global_load_lds( \
    (const __attribute__((address_space(1))) void*)(src), \
    (__attribute__((address_space(3))) void*)(dst), 16, 0, 0)

__launch_bounds__(256, 2)
__global__ void conv3d_v20(const unsigned short* __restrict__ xpad,
                           const short8* __restrict__ wbuf,
                           const float* __restrict__ bias,
                           float* __restrict__ out) {
    // x-tile 56160B + 256B pad + A 4-slot buffer 4x4096B = 72.8 KB
    __shared__ __align__(16) unsigned short xl[ALDS_SH + 4 * 2048];

    const int tid = threadIdx.x;
    // bijective XCD swizzle: 896 = 8 * 112
    int b = ((blockIdx.x & 7) * 112) + (blockIdx.x >> 3);
    const int ht  = b % 14;  b /= 14;
    const int ddp = b & 7;
    const int n   = b >> 3;
    const int ho0 = ht * 4;          // 4 ho rows per block
    const int dd0 = ddp * 2;

    const int lane = tid & 63;
    const int wid  = tid >> 6;          // 0..3

    // ---- stage x: 18 (c,plane) segments of 3120 B ----
    {
        const size_t nb = (size_t)(n * CI) * XP_D;
        for (int s = wid; s < 18; s += 4) {
            const int c = s / 6;
            const int p = s - c * 6;
            const char* gsrc = (const char*)(xpad +
                ((nb + (size_t)c * XP_D + (dd0 + p)) * XP_H + 2 * ho0) * XP_ROW)
                + lane * 16;
            char* ldst = (char*)&xl[s * SEG_SH];
            GLDS(gsrc, ldst);
            GLDS(gsrc + 1024, ldst + 1024);
            GLDS(gsrc + 2048, ldst + 2048);
            if (lane < 3) GLDS(gsrc + 3072, ldst + 3072);
        }
    }
    // ---- stage A(0) slot0 (wave0) and A(1) slot1 (wave1), hide under drain ----
    if (wid == 0) {
        const char* gs = (const char*)wbuf + lane * 16;
        char* ad = (char*)&xl[ALDS_SH];
        GLDS(gs, ad); GLDS(gs + 1024, ad + 1024);
        GLDS(gs + 2048, ad + 2048); GLDS(gs + 3072, ad + 3072);
    } else if (wid == 1) {
        const char* gs = (const char*)(wbuf + 4 * 64) + lane * 16;
        char* ad = (char*)&xl[ALDS_SH] + 4096;
        GLDS(gs, ad); GLDS(gs + 1024, ad + 1024);
        GLDS(gs + 2048, ad + 2048); GLDS(gs + 3072, ad + 3072);
    }
    __syncthreads();

    // ---- wave roles: ddl x hp2; wave = 64co x 2ho x 64wo ----
    const int ddl   = wid & 1;
    const int hp2   = wid >> 1;         // ho pair 0,1
    const int l31   = lane & 31;
    const int hl    = lane >> 5;        // k-half within ks
    const int l15   = l31 & 15;
    const int hosub = l31 >> 4;         // ho sub-row within pair
    const int hoL   = hp2 * 2 + hosub;  // 0..3
    // per-lane B base: 16B-aligned (4*l15 dwords)
    const int tspB  = ddl * SEG_DW + hoL * (2 * ROW_DW) + 4 * l15;   // dwords

    f32x16 acc[2][4];
    #pragma unroll
    for (int a = 0; a < 2; ++a) {
        f32x16 bv;
        #pragma unroll
        for (int g = 0; g < 16; ++g)
            bv[g] = bias[a * 32 + (g & 3) + 8 * (g >> 2) + 4 * hl];
        #pragma unroll
        for (int f = 0; f < 4; ++f) acc[a][f] = bv;
    }

    const unsigned* xlu = reinterpret_cast<const unsigned*>(xl);
    union BxU { unsigned u[4]; short8 s; };

    // per-chunk (fully unrolled): 2 pool-b128 per ks + 4 A-b128, 16 MFMAs.
    // A slots rotate mod 4; stage A(ch+2) each chunk; barrier every 2 chunks.
    #pragma unroll
    for (int ch = 0; ch < NCH; ++ch) {
        // stage A(ch+2) -> slot (ch+2)&3 (one wave, round-robin over 4 waves)
        if (ch + 2 < NCH && wid == ((ch + 2) & 3)) {
            const char* gs = (const char*)(wbuf + (size_t)(ch + 2) * 4 * 64) + lane * 16;
            char* ad = (char*)&xl[ALDS_SH] + ((ch + 2) & 3) * 4096;
            GLDS(gs, ad); GLDS(gs + 1024, ad + 1024);
            GLDS(gs + 2048, ad + 2048); GLDS(gs + 3072, ad + 3072);
        }
        const int nks = (ch == NCH - 1) ? 1 : 2;
        // B pools: 2 x ds_read_b128 per ks, 16B-aligned by construction
        unsigned p0[8], p1[8];
        {
            const int r0 = ch * 4;
            const int base = rb2(r0) + hl * (rb2(r0 + 1) - rb2(r0));
            const unsigned* xp = xlu + base + tspB;
            uint4 va = *reinterpret_cast<const uint4*>(xp);
            uint4 vb = *reinterpret_cast<const uint4*>(xp + 4);
            p0[0] = va.x; p0[1] = va.y; p0[2] = va.z; p0[3] = va.w;
            p0[4] = vb.x; p0[5] = vb.y; p0[6] = vb.z; p0[7] = vb.w;
        }
        if (nks == 2) {
            const int r0 = ch * 4 + 2;
            const int base = rb2(r0) + hl * (rb2(r0 + 1) - rb2(r0));
            const unsigned* xp = xlu + base + tspB;
            uint4 va = *reinterpret_cast<const uint4*>(xp);
            uint4 vb = *reinterpret_cast<const uint4*>(xp + 4);
            p1[0] = va.x; p1[1] = va.y; p1[2] = va.z; p1[3] = va.w;
            p1[4] = vb.x; p1[5] = vb.y; p1[6] = vb.z; p1[7] = vb.w;
        }
        // A(ch) from LDS slot ch&3
        short8 As[4];
        {
            const char* ab = (const char*)&xl[ALDS_SH] + (ch & 3) * 4096 + lane * 16;
            As[0] = *reinterpret_cast<const short8*>(ab);
            As[1] = *reinterpret_cast<const short8*>(ab + 1024);
            if (nks == 2) {
                As[2] = *reinterpret_cast<const short8*>(ab + 2048);
                As[3] = *reinterpret_cast<const short8*>(ab + 3072);
            }
        }
        __builtin_amdgcn_s_setprio(1);
        #pragma unroll
        for (int f = 0; f < 4; ++f) {
            BxU bx;
            bx.u[0] = p0[f]; bx.u[1] = p0[f + 1];
            bx.u[2] = p0[f + 2]; bx.u[3] = p0[f + 3];
            acc[0][f] = MFMA32(As[0], bx.s, acc[0][f]);
            acc[1][f] = MFMA32(As[1], bx.s, acc[1][f]);
        }
        if (nks == 2) {
            #pragma unroll
            for (int f = 0; f < 4; ++f) {
                BxU bx;
                bx.u[0] = p1[f]; bx.u[1] = p1[f + 1];
                bx.u[2] = p1[f + 2]; bx.u[3] = p1[f + 3];
                acc[0][f] = MFMA32(As[2], bx.s, acc[0][f]);
                acc[1][f] = MFMA32(As[3], bx.s, acc[1][f]);
            }
        }
        __builtin_amdgcn_s_setprio(0);
        // barrier every 2 chunks (end of odd chunk): bounds wave skew
        if ((ch & 1) && ch != NCH - 1) __syncthreads();
    }

    // ---- store: D row=(g&3)+8*(g>>2)+4*hl; col n=l31 -> wo = 4*l15+f,
    //      ho = ho0 + hoL. Lanes with l15 >= 14 (wo >= 56) are dead.
    const int dd = dd0 + ddl;
    const int ho = ho0 + hoL;
    const size_t obase = (size_t)n * CO * DHWO + (size_t)dd * 3136 + ho * WO;
    if (l15 < 14) {
        #pragma unroll
        for (int f = 0; f < 4; ++f) {
            const int wo = 4 * l15 + f;
            #pragma unroll
            for (int a = 0; a < 2; ++a) {
                #pragma unroll
                for (int g = 0; g < 16; ++g) {
                    const int co = a * 32 + (g & 3) + 8 * (g >> 2) + 4 * hl;
                    out[obase + (size_t)co * DHWO + wo] = acc[a][f][g];
                }
            }
        }
    }
}

// =================== fallback (round-5 kernel, 16x16 path) ===================
#define FB_LR 13
#define FB_LROWS 234
#define FB_LWS 144
#define FB_XLSZ (FB_LROWS*FB_LWS)
#define MFMA16(A, B, C) __builtin_amdgcn_mfma_f32_16x16x32_bf16(A, B, C, 0, 0, 0)

__global__ void prep_weights_fb(const float* __restrict__ wgt, short8* __restrict__ wbuf) {
    const int t    = blockIdx.x * 64 + threadIdx.x;
    const int lane = t & 63;
    const int cf   = t >> 6;
    const int l15  = lane & 15;
    const int kgrp = lane >> 4;
    const int co   = (cf & 3) * 16 + l15;
    const int rr   = (cf >> 2) * 4 + kgrp;
    const int rc   = (rr < NROW) ? rr : (NROW - 1);
    const int c    = rc / 35;
    const int kd   = (rc / 7) % 5;
    const int kh   = rc % 7;
    const float* wsrc = wgt + (((co * CI + c) * 5 + kd) * 7 + kh) * 7;
    short8 v;
    #pragma unroll
    for (int j = 0; j < 8; ++j) {
        float w = (rr < NROW && j < 7) ? wsrc[j] : 0.0f;
        v[j] = (short)f2bf(w);
    }
    wbuf[(size_t)cf * 64 + lane] = v;
}

__launch_bounds__(512, 2)
__global__ void conv3d_mfma4(const float* __restrict__ x,
                             const short8* __restrict__ wbuf,
                             const float* __restrict__ bias,
                             float* __restrict__ out) {
    __shared__ unsigned short xl[FB_XLSZ];
    __shared__ int rowg[FB_LROWS];
    __shared__ unsigned short tabr[108];

    const int tid = threadIdx.x;
    int b = blockIdx.x;
    const int ht  = b % 14;  b /= 14;
    const int ddp = b % 8;
    const int n   = b / 8;
    const int ho0 = ht * 4;
    const int dd0 = ddp * 2;

    if (tid < FB_LROWS) {
        const int c   = tid / (6 * FB_LR);
        const int rem = tid - c * (6 * FB_LR);
        const int p   = rem / FB_LR;
        const int rl  = rem - p * FB_LR;
        const int din = dd0 - 2 + p;
        const int hin = 2 * ho0 - 3 + rl;
        const bool ok = ((unsigned)din < (unsigned)DI) && ((unsigned)hin < (unsigned)HI);
        rowg[tid] = ok ? ((n * CI + c) * DI + din) * HW_IN + hin * WI : -1;
    }
    if (tid < 108) {
        const int rc = (tid < NROW) ? tid : (NROW - 1);
        const int c  = rc / 35;
        const int kd = (rc / 7) % 5;
        const int kh = rc % 7;
        tabr[tid] = (unsigned short)(((c * 6 + kd) * FB_LR + kh) * FB_LWS);
    }
    __syncthreads();

    const int lane = tid & 63;
    const int wid  = tid >> 6;

    for (int row = wid; row < FB_LROWS; row += 8) {
        const int base = rowg[row];
        unsigned short* dst = &xl[row * FB_LWS];
        if (lane < 57) {
            float v0 = 0.0f, v1 = 0.0f;
            const int w0 = 2 * lane - 1;
            if (base >= 0) {
                if (lane >= 1)  v0 = x[base + w0];
                if (lane <= 55) v1 = x[base + w0 + 1];
            }
            *reinterpret_cast<unsigned*>(&dst[2 * lane + 2]) = pk_bf16(v0, v1);
        } else {
            const int dw = (lane == 57) ? 0 : lane;
            *reinterpret_cast<unsigned*>(&dst[2 * dw]) = 0u;
        }
    }
    __syncthreads();

    const int ddl  = wid & 1;
    const int hoL  = wid >> 1;
    const int l15  = lane & 15;
    const int kgrp = lane >> 4;
    const int woff = ddl * (FB_LR * FB_LWS) + hoL * (2 * FB_LWS);

    f32x4 acc[4][4];
    #pragma unroll
    for (int a = 0; a < 4; ++a) {
        f32x4 bv;
        #pragma unroll
        for (int r = 0; r < 4; ++r) bv[r] = bias[a * 16 + kgrp * 4 + r];
        #pragma unroll
        for (int f = 0; f < 4; ++f) acc[a][f] = bv;
    }

    const short8* wbp = wbuf + lane;
    short8 Acur[4], Anxt[4];
    #pragma unroll
    for (int a = 0; a < 4; ++a) Acur[a] = wbp[a * 64];
    int tb = (int)tabr[kgrp] + woff;

    const unsigned* xlu = reinterpret_cast<const unsigned*>(xl);

    for (int ch = 0; ch < NCH; ++ch) {
        int tbn = 0;
        if (ch + 1 < NCH) {
            tbn = (int)tabr[(ch + 1) * 4 + kgrp] + woff;
            #pragma unroll
            for (int a = 0; a < 4; ++a) Anxt[a] = wbp[((ch + 1) * 4 + a) * 64];
        }
        const unsigned* xp = xlu + (tb >> 1) + l15;
        union { unsigned u[4]; short8 s; } bx[4];
        #pragma unroll
        for (int f = 0; f < 4; ++f) {
            const unsigned* p = xp + f * 16;
            bx[f].u[0] = p[0]; bx[f].u[1] = p[1];
            bx[f].u[2] = p[2]; bx[f].u[3] = p[3];
        }
        #pragma unroll
        for (int f = 0; f < 4; ++f) {
            acc[0][f] = MFMA16(Acur[0], bx[f].s, acc[0][f]);
            acc[1][f] = MFMA16(Acur[1], bx[f].s, acc[1][f]);
            acc[2][f] = MFMA16(Acur[2], bx[f].s, acc[2][f]);
            acc[3][f] = MFMA16(Acur[3], bx[f].s, acc[3][f]);
        }
        tb = tbn;
        #pragma unroll
        for (int a = 0; a < 4; ++a) Acur[a] = Anxt[a];
    }

    const int dd = dd0 + ddl;
    const int ho = ho0 + hoL;
    #pragma unroll
    for (int f = 0; f < 4; ++f) {
        const int wo = f * 16 + l15;
        if (f < 3 || l15 < 8) {
            float* op = out + (((size_t)(n * CO) * DO_ + dd) * HO + ho) * WO + wo;
            #pragma unroll
            for (int a = 0; a < 4; ++a) {
                const int co = a * 16 + kgrp * 4;
                #pragma unroll
                for (int r = 0; r < 4; ++r)
                    op[(size_t)(co + r) * DHWO] = acc[a][f][r];
            }
        }
    }
}

extern "C" void kernel_launch(void* const* d_in, const int* in_sizes, int n_in,
                              void* d_out, int out_size, void* d_ws, size_t ws_size,
                              hipStream_t stream) {
    const float* x    = (const float*)d_in[0];
    const float* wgt  = (const float*)d_in[1];
    const float* bias = (const float*)d_in[2];
    float* out        = (float*)d_out;

    if (ws_size >= (size_t)WS_NEED) {
        unsigned* xpad = (unsigned*)d_ws;
        short8* wbuf   = (short8*)((char*)d_ws + WBUF_OFF);
        hipLaunchKernelGGL(prep_all, dim3(XP_BLOCKS + 27, 1, 1), dim3(256, 1, 1), 0,
                           stream, x, wgt, xpad, wbuf);
        // grid: 14 ho-tiles * 8 dd-pairs * 8 n = 896 blocks of 256 threads
        hipLaunchKernelGGL(conv3d_v20, dim3(896, 1, 1), dim3(256, 1, 1), 0, stream,
                           (const unsigned short*)xpad, wbuf, bias, out);
    } else {
        short8* wbuf = (short8*)d_ws;
        hipLaunchKernelGGL(prep_weights_fb, dim3(NCH * 4, 1, 1), dim3(64, 1, 1), 0,
                           stream, wgt, wbuf);
        hipLaunchKernelGGL(conv3d_mfma4, dim3(896, 1, 1), dim3(512, 1, 1), 0, stream,
                           x, wbuf, bias, out);
    }
}

// Round 21
// 63.736 us; speedup vs baseline: 1.2260x; 1.2260x over previous
//
#include <hip/hip_runtime.h>

// Conv3D implicit GEMM, round 21: REVERT to round-19 (best: 64.5 µs total).
// A shared via LDS (4-slot rotation, race-free: skew<=2 x distance-2 => 4
// slots), barrier every 2 chunks, a2f2 32x32 MFMA waves, zero-tail skip,
// XCD swizzle, pre-padded bf16 xpad + fragment-ready weights in d_ws.
// x (8,3,16,112,112) f32, w (64,3,5,7,7), bias (64,) -> out (8,64,16,56,56) f32

typedef __attribute__((ext_vector_type(8)))  short short8;
typedef __attribute__((ext_vector_type(4)))  float f32x4;
typedef __attribute__((ext_vector_type(16))) float f32x16;

#define CI 3
#define DI 16
#define HI 112
#define WI 112
#define CO 64
#define DO_ 16
#define HO 56
#define WO 56
#define HW_IN 12544
#define DHWO 50176

#define NROW 105
#define NCH 27

// xpad: bf16 [8][3][20 dpad][119 hpad][120 slots]; slot s = win s-3
#define XP_ROW 120
#define XP_H   119
#define XP_D   20
#define XPAD_BYTES  (8*3*XP_D*XP_H*XP_ROW*2)   // 13,708,800
#define WBUF_OFF    XPAD_BYTES
#define WS_NEED     (WBUF_OFF + NCH*4*64*16 + 4096)

#define LR 13               // staged h-rows per (c,plane): 2*4ho + 5
#define SEG_SH (LR*XP_ROW)  // 1560 shorts (3120 B)
#define SEG_DW (SEG_SH/2)   // 780
#define ROW_DW (XP_ROW/2)   // 60
#define ALDS_SH (18*SEG_SH + 128)   // short-index of A LDS base (after pad)

__device__ __forceinline__ unsigned short f2bf(float f) {
    unsigned u = __float_as_uint(f);
    return (unsigned short)((u + 0x7FFFu + ((u >> 16) & 1u)) >> 16);
}
__device__ __forceinline__ unsigned pk_bf16(float a, float b) {
    unsigned r;
    asm("v_cvt_pk_bf16_f32 %0, %1, %2" : "=v"(r) : "v"(a), "v"(b));
    return r;
}

// clamped row -> LDS dword base within (ddl=0, hp=0)
__device__ __forceinline__ constexpr int rb2(int r) {
    const int rc = (r > 104) ? 104 : r;
    const int c  = rc / 35;
    const int kd = (rc / 7) % 5;
    const int kh = rc % 7;
    return (c * 6 + kd) * SEG_DW + kh * ROW_DW;
}

// ---------- fused prep: xpad (15 s8-groups/row) + weights 32x32 layout ----------
#define XP_THREADS (8*3*XP_D*XP_H*15)   // 856,800
#define XP_BLOCKS  3347

__global__ void prep_all(const float* __restrict__ x, const float* __restrict__ wgt,
                         unsigned* __restrict__ xp, short8* __restrict__ wbuf) {
    if (blockIdx.x < XP_BLOCKS) {
        const int g = blockIdx.x * 256 + threadIdx.x;
        if (g >= XP_THREADS) return;
        const int s8 = g % 15;
        int r = g / 15;
        const int hp = r % XP_H; r /= XP_H;
        const int dp = r % XP_D; r /= XP_D;
        const int c  = r % 3;
        const int n  = r / 3;
        const int din = dp - 2, hin = hp - 3;
        const bool rowok = ((unsigned)din < (unsigned)DI) && ((unsigned)hin < (unsigned)HI);
        float v[8];
        const int w0 = 8 * s8 - 3;
        if (rowok && s8 >= 1 && s8 <= 13) {
            const float* xr = x + ((n * CI + c) * DI + din) * HW_IN + hin * WI + w0;
            #pragma unroll
            for (int j = 0; j < 8; ++j) v[j] = xr[j];
        } else if (rowok && (s8 == 0 || s8 == 14)) {
            const float* xr = x + ((n * CI + c) * DI + din) * HW_IN + hin * WI;
            #pragma unroll
            for (int j = 0; j < 8; ++j) {
                const int w = w0 + j;
                v[j] = ((unsigned)w < (unsigned)WI) ? xr[w] : 0.0f;
            }
        } else {
            #pragma unroll
            for (int j = 0; j < 8; ++j) v[j] = 0.0f;
        }
        uint4 o;
        o.x = pk_bf16(v[0], v[1]); o.y = pk_bf16(v[2], v[3]);
        o.z = pk_bf16(v[4], v[5]); o.w = pk_bf16(v[6], v[7]);
        *reinterpret_cast<uint4*>(xp + 4 * (size_t)g) = o;
    } else {
        // weights -> 32x32 fragment layout: frag cf = ch*4 + ks*2 + a
        // lane: co = a*32 + (lane&31), row r = ch*4 + ks*2 + (lane>>5), kw = j
        const int t = (blockIdx.x - XP_BLOCKS) * 256 + threadIdx.x;  // 0..6911
        const int lane = t & 63;
        const int cf   = t >> 6;           // 0..107
        const int q    = cf & 3;
        const int a    = q & 1;
        const int ks   = q >> 1;
        const int ch   = cf >> 2;
        const int l31  = lane & 31;
        const int hl   = lane >> 5;
        const int co   = a * 32 + l31;
        const int r    = ch * 4 + ks * 2 + hl;
        const int rc   = (r > 104) ? 104 : r;
        const int c    = rc / 35;
        const int kd   = (rc / 7) % 5;
        const int kh   = rc % 7;
        const float* wsrc = wgt + (((co * CI + c) * 5 + kd) * 7 + kh) * 7;
        short8 v;
        #pragma unroll
        for (int j = 0; j < 8; ++j) {
            float w = (r < NROW && j < 7) ? wsrc[j] : 0.0f;
            v[j] = (short)f2bf(w);
        }
        wbuf[(size_t)cf * 64 + lane] = v;
    }
}

#define MFMA32(A, B, C) __builtin_amdgcn_mfma_f32_32x32x16_bf16(A, B, C, 0, 0, 0)
#define GLDS(src, dst) __builtin_amdgcn_global_load_lds( \
    (const __attribute__((address_space(1))) void*)(src), \
    (__attribute__((address_space(3))) void*)(dst), 16, 0, 0)

__launch_bounds__(512, 4)
__global__ void conv3d_v19(const unsigned short* __restrict__ xpad,
                           const short8* __restrict__ wbuf,
                           const float* __restrict__ bias,
                           float* __restrict__ out) {
    // x-tile 56160B + 256B pad + A 4-slot buffer 4x4096B = 72.8 KB
    __shared__ __align__(16) unsigned short xl[ALDS_SH + 4 * 2048];

    const int tid = threadIdx.x;
    // bijective XCD swizzle: 896 = 8 * 112
    int b = ((blockIdx.x & 7) * 112) + (blockIdx.x >> 3);
    const int ht  = b % 14;  b /= 14;
    const int ddp = b & 7;
    const int n   = b >> 3;
    const int ho0 = ht * 4;          // 4 ho rows per block
    const int dd0 = ddp * 2;

    const int lane = tid & 63;
    const int wid  = tid >> 6;          // 0..7

    // ---- stage x: 18 (c,plane) segments of 3120 B ----
    {
        const size_t nb = (size_t)(n * CI) * XP_D;
        for (int s = wid; s < 18; s += 8) {
            const int c = s / 6;
            const int p = s - c * 6;
            const char* gsrc = (const char*)(xpad +
                ((nb + (size_t)c * XP_D + (dd0 + p)) * XP_H + 2 * ho0) * XP_ROW)
                + lane * 16;
            char* ldst = (char*)&xl[s * SEG_SH];
            GLDS(gsrc, ldst);
            GLDS(gsrc + 1024, ldst + 1024);
            GLDS(gsrc + 2048, ldst + 2048);
            if (lane < 3) GLDS(gsrc + 3072, ldst + 3072);
        }
    }
    // ---- stage A(0) slot0 (wave0) and A(1) slot1 (wave1), hide under drain ----
    if (wid == 0) {
        const char* gs = (const char*)wbuf + lane * 16;
        char* ad = (char*)&xl[ALDS_SH];
        GLDS(gs, ad); GLDS(gs + 1024, ad + 1024);
        GLDS(gs + 2048, ad + 2048); GLDS(gs + 3072, ad + 3072);
    } else if (wid == 1) {
        const char* gs = (const char*)(wbuf + 4 * 64) + lane * 16;
        char* ad = (char*)&xl[ALDS_SH] + 4096;
        GLDS(gs, ad); GLDS(gs + 1024, ad + 1024);
        GLDS(gs + 2048, ad + 2048); GLDS(gs + 3072, ad + 3072);
    }
    __syncthreads();

    // ---- wave roles: ddl x hp; wave = 64co x 64wo (56 real), ho = ho0+hp ----
    const int ddl = wid & 1;
    const int hp  = wid >> 1;           // 0..3
    const int l31 = lane & 31;
    const int hl  = lane >> 5;
    const int tspB = ddl * SEG_DW + hp * (2 * ROW_DW) + l31;   // dwords

    f32x16 acc[2][2];
    #pragma unroll
    for (int a = 0; a < 2; ++a) {
        f32x16 bv;
        #pragma unroll
        for (int g = 0; g < 16; ++g)
            bv[g] = bias[a * 32 + (g & 3) + 8 * (g >> 2) + 4 * hl];
        acc[a][0] = bv; acc[a][1] = bv;
    }

    const unsigned* xlu = reinterpret_cast<const unsigned*>(xl);
    union BxU { unsigned u[4]; short8 s; };

    // per-chunk body (fully unrolled): B reads first, then A, then MFMAs.
    // A slots rotate mod 4; stage A(ch+2) each chunk; barrier every 2 chunks.
    // Safety: skew bounded to chunk-pair {2k,2k+1}; staged slots {(2k+2)&3,
    // (2k+3)&3} disjoint from read slots {2k&3,(2k+1)&3}; __syncthreads'
    // vmcnt(0) drain orders stage-write -> read across windows.
    #pragma unroll
    for (int ch = 0; ch < NCH; ++ch) {
        // stage A(ch+2) -> slot (ch+2)&3 (one wave, round-robin)
        if (ch + 2 < NCH && wid == ((ch + 2) & 7)) {
            const char* gs = (const char*)(wbuf + (size_t)(ch + 2) * 4 * 64) + lane * 16;
            char* ad = (char*)&xl[ALDS_SH] + ((ch + 2) & 3) * 4096;
            GLDS(gs, ad); GLDS(gs + 1024, ad + 1024);
            GLDS(gs + 2048, ad + 2048); GLDS(gs + 3072, ad + 3072);
        }
        const int nks = (ch == NCH - 1) ? 1 : 2;
        // B(ch): exact compile-time row bases, hl-select (B first: longest chain)
        BxU Bs[4];
        #pragma unroll
        for (int ks = 0; ks < 2; ++ks) {
            if (ks < nks) {
                const int r0 = ch * 4 + ks * 2;
                const int b0 = rb2(r0);
                const int b1 = rb2(r0 + 1);
                const int base = b0 + hl * (b1 - b0);
                const unsigned* xp = xlu + base + tspB;
                #pragma unroll
                for (int f = 0; f < 2; ++f) {
                    const unsigned* p = xp + f * 32;
                    Bs[ks * 2 + f].u[0] = p[0];
                    Bs[ks * 2 + f].u[1] = p[1];
                    Bs[ks * 2 + f].u[2] = p[2];
                    Bs[ks * 2 + f].u[3] = p[3];
                }
            }
        }
        // A(ch) from LDS slot ch&3 (skip zero frags of last chunk)
        short8 As[4];
        {
            const char* ab = (const char*)&xl[ALDS_SH] + (ch & 3) * 4096 + lane * 16;
            As[0] = *reinterpret_cast<const short8*>(ab);
            As[1] = *reinterpret_cast<const short8*>(ab + 1024);
            if (nks == 2) {
                As[2] = *reinterpret_cast<const short8*>(ab + 2048);
                As[3] = *reinterpret_cast<const short8*>(ab + 3072);
            }
        }
        __builtin_amdgcn_s_setprio(1);
        #pragma unroll
        for (int a = 0; a < 2; ++a) {
            #pragma unroll
            for (int f = 0; f < 2; ++f) {
                acc[a][f] = MFMA32(As[0 + a], Bs[0 + f].s, acc[a][f]);
                if (nks == 2)
                    acc[a][f] = MFMA32(As[2 + a], Bs[2 + f].s, acc[a][f]);
            }
        }
        __builtin_amdgcn_s_setprio(0);
        // barrier every 2 chunks (end of odd chunk): bounds wave skew
        if ((ch & 1) && ch != NCH - 1) __syncthreads();
    }

    // ---- store: D row=(g&3)+8*(g>>2)+4*hl, col wo = f*32 + l31 ----
    const int dd = dd0 + ddl;
    const int ho = ho0 + hp;
    const size_t obase = (size_t)n * CO * DHWO + (size_t)dd * 3136 + ho * WO;
    #pragma unroll
    for (int f = 0; f < 2; ++f) {
        const int wo = f * 32 + l31;
        if (f == 0 || l31 < 24) {
            #pragma unroll
            for (int a = 0; a < 2; ++a) {
                #pragma unroll
                for (int g = 0; g < 16; ++g) {
                    const int co = a * 32 + (g & 3) + 8 * (g >> 2) + 4 * hl;
                    out[obase + (size_t)co * DHWO + wo] = acc[a][f][g];
                }
            }
        }
    }
}

// =================== fallback (round-5 kernel, 16x16 path) ===================
#define FB_LR 13
#define FB_LROWS 234
#define FB_LWS 144
#define FB_XLSZ (FB_LROWS*FB_LWS)
#define MFMA16(A, B, C) __builtin_amdgcn_mfma_f32_16x16x32_bf16(A, B, C, 0, 0, 0)

__global__ void prep_weights_fb(const float* __restrict__ wgt, short8* __restrict__ wbuf) {
    const int t    = blockIdx.x * 64 + threadIdx.x;
    const int lane = t & 63;
    const int cf   = t >> 6;
    const int l15  = lane & 15;
    const int kgrp = lane >> 4;
    const int co   = (cf & 3) * 16 + l15;
    const int rr   = (cf >> 2) * 4 + kgrp;
    const int rc   = (rr < NROW) ? rr : (NROW - 1);
    const int c    = rc / 35;
    const int kd   = (rc / 7) % 5;
    const int kh   = rc % 7;
    const float* wsrc = wgt + (((co * CI + c) * 5 + kd) * 7 + kh) * 7;
    short8 v;
    #pragma unroll
    for (int j = 0; j < 8; ++j) {
        float w = (rr < NROW && j < 7) ? wsrc[j] : 0.0f;
        v[j] = (short)f2bf(w);
    }
    wbuf[(size_t)cf * 64 + lane] = v;
}

__launch_bounds__(512, 2)
__global__ void conv3d_mfma4(const float* __restrict__ x,
                             const short8* __restrict__ wbuf,
                             const float* __restrict__ bias,
                             float* __restrict__ out) {
    __shared__ unsigned short xl[FB_XLSZ];
    __shared__ int rowg[FB_LROWS];
    __shared__ unsigned short tabr[108];

    const int tid = threadIdx.x;
    int b = blockIdx.x;
    const int ht  = b % 14;  b /= 14;
    const int ddp = b % 8;
    const int n   = b / 8;
    const int ho0 = ht * 4;
    const int dd0 = ddp * 2;

    if (tid < FB_LROWS) {
        const int c   = tid / (6 * FB_LR);
        const int rem = tid - c * (6 * FB_LR);
        const int p   = rem / FB_LR;
        const int rl  = rem - p * FB_LR;
        const int din = dd0 - 2 + p;
        const int hin = 2 * ho0 - 3 + rl;
        const bool ok = ((unsigned)din < (unsigned)DI) && ((unsigned)hin < (unsigned)HI);
        rowg[tid] = ok ? ((n * CI + c) * DI + din) * HW_IN + hin * WI : -1;
    }
    if (tid < 108) {
        const int rc = (tid < NROW) ? tid : (NROW - 1);
        const int c  = rc / 35;
        const int kd = (rc / 7) % 5;
        const int kh = rc % 7;
        tabr[tid] = (unsigned short)(((c * 6 + kd) * FB_LR + kh) * FB_LWS);
    }
    __syncthreads();

    const int lane = tid & 63;
    const int wid  = tid >> 6;

    for (int row = wid; row < FB_LROWS; row += 8) {
        const int base = rowg[row];
        unsigned short* dst = &xl[row * FB_LWS];
        if (lane < 57) {
            float v0 = 0.0f, v1 = 0.0f;
            const int w0 = 2 * lane - 1;
            if (base >= 0) {
                if (lane >= 1)  v0 = x[base + w0];
                if (lane <= 55) v1 = x[base + w0 + 1];
            }
            *reinterpret_cast<unsigned*>(&dst[2 * lane + 2]) = pk_bf16(v0, v1);
        } else {
            const int dw = (lane == 57) ? 0 : lane;
            *reinterpret_cast<unsigned*>(&dst[2 * dw]) = 0u;
        }
    }
    __syncthreads();

    const int ddl  = wid & 1;
    const int hoL  = wid >> 1;
    const int l15  = lane & 15;
    const int kgrp = lane >> 4;
    const int woff = ddl * (FB_LR * FB_LWS) + hoL * (2 * FB_LWS);

    f32x4 acc[4][4];
    #pragma unroll
    for (int a = 0; a < 4; ++a) {
        f32x4 bv;
        #pragma unroll
        for (int r = 0; r < 4; ++r) bv[r] = bias[a * 16 + kgrp * 4 + r];
        #pragma unroll
        for (int f = 0; f < 4; ++f) acc[a][f] = bv;
    }

    const short8* wbp = wbuf + lane;
    short8 Acur[4], Anxt[4];
    #pragma unroll
    for (int a = 0; a < 4; ++a) Acur[a] = wbp[a * 64];
    int tb = (int)tabr[kgrp] + woff;

    const unsigned* xlu = reinterpret_cast<const unsigned*>(xl);

    for (int ch = 0; ch < NCH; ++ch) {
        int tbn = 0;
        if (ch + 1 < NCH) {
            tbn = (int)tabr[(ch + 1) * 4 + kgrp] + woff;
            #pragma unroll
            for (int a = 0; a < 4; ++a) Anxt[a] = wbp[((ch + 1) * 4 + a) * 64];
        }
        const unsigned* xp = xlu + (tb >> 1) + l15;
        union { unsigned u[4]; short8 s; } bx[4];
        #pragma unroll
        for (int f = 0; f < 4; ++f) {
            const unsigned* p = xp + f * 16;
            bx[f].u[0] = p[0]; bx[f].u[1] = p[1];
            bx[f].u[2] = p[2]; bx[f].u[3] = p[3];
        }
        #pragma unroll
        for (int f = 0; f < 4; ++f) {
            acc[0][f] = MFMA16(Acur[0], bx[f].s, acc[0][f]);
            acc[1][f] = MFMA16(Acur[1], bx[f].s, acc[1][f]);
            acc[2][f] = MFMA16(Acur[2], bx[f].s, acc[2][f]);
            acc[3][f] = MFMA16(Acur[3], bx[f].s, acc[3][f]);
        }
        tb = tbn;
        #pragma unroll
        for (int a = 0; a < 4; ++a) Acur[a] = Anxt[a];
    }

    const int dd = dd0 + ddl;
    const int ho = ho0 + hoL;
    #pragma unroll
    for (int f = 0; f < 4; ++f) {
        const int wo = f * 16 + l15;
        if (f < 3 || l15 < 8) {
            float* op = out + (((size_t)(n * CO) * DO_ + dd) * HO + ho) * WO + wo;
            #pragma unroll
            for (int a = 0; a < 4; ++a) {
                const int co = a * 16 + kgrp * 4;
                #pragma unroll
                for (int r = 0; r < 4; ++r)
                    op[(size_t)(co + r) * DHWO] = acc[a][f][r];
            }
        }
    }
}

extern "C" void kernel_launch(void* const* d_in, const int* in_sizes, int n_in,
                              void* d_out, int out_size, void* d_ws, size_t ws_size,
                              hipStream_t stream) {
    const float* x    = (const float*)d_in[0];
    const float* wgt  = (const float*)d_in[1];
    const float* bias = (const float*)d_in[2];
    float* out        = (float*)d_out;

    if (ws_size >= (size_t)WS_NEED) {
        unsigned* xpad = (unsigned*)d_ws;
        short8* wbuf   = (short8*)((char*)d_ws + WBUF_OFF);
        hipLaunchKernelGGL(prep_all, dim3(XP_BLOCKS + 27, 1, 1), dim3(256, 1, 1), 0,
                           stream, x, wgt, xpad, wbuf);
        // grid: 14 ho-tiles * 8 dd-pairs * 8 n = 896 blocks of 512 threads
        hipLaunchKernelGGL(conv3d_v19, dim3(896, 1, 1), dim3(512, 1, 1), 0, stream,
                           (const unsigned short*)xpad, wbuf, bias, out);
    } else {
        short8* wbuf = (short8*)d_ws;
        hipLaunchKernelGGL(prep_weights_fb, dim3(NCH * 4, 1, 1), dim3(64, 1, 1), 0,
                           stream, wgt, wbuf);
        hipLaunchKernelGGL(conv3d_mfma4, dim3(896, 1, 1), dim3(512, 1, 1), 0, stream,
                           x, wbuf, bias, out);
    }
}